// Round 1
// 112.971 us; speedup vs baseline: 1.0272x; 1.0272x over previous
//
#include <hip/hip_runtime.h>
#include <math.h>

// AFM forward: out[b] = linear(b) + softmax-weighted pair-interaction projection.
// B=4096, F=26, d=64, P=325 pairs, af=64.
//
// R8: single-kernel version. R7 rocprof: top-5 dispatches are all harness
// 256-MiB workspace-poison fills (~43 us each); afm_kernel itself is below
// that. Remaining controllable cost: prep_kernel launch + gap serialized
// ahead of afm, and the workspace round-trip. Fix: fold W1^T (f32->f16
// transpose via LDS, block-cooperative) and the pair table (672 B) into
// afm's prologue; drop prep_kernel and d_ws usage entirely. Cost: one
// __syncthreads() (previously barrier-free) + 16 KB L2-hot W1 read/block.
// Also: logit reduction restructured from a serial 16-deep fmaf chain
// (~64 cyc dep/m-tile) to per-nt partials + 2-level tree (~20 cyc) --
// R6 showed wave lifetime is dependency-stall bound.
// 1 row/wave, 4 waves/block, block barrier only at prologue.

#define NF 26
#define NP 325
#define NMT 21           // 21 m-tiles of 16 pairs (336, pads -> -inf)
#define ED 64
#define AF 64
#define NDENSE 13
#define WPB 4            // waves (rows) per block
#define BLOCK (WPB * 64)
#define ESTRIDE 72       // f16 elems per emb row: 144 B (16B-aligned rows)
#define WSTRIDE 72       // f16 elems per w1t row: 144 B (16B-aligned rows)

typedef __attribute__((ext_vector_type(8))) _Float16 half8;
typedef __attribute__((ext_vector_type(4))) float f32x4;

__global__ __launch_bounds__(BLOCK, 4)   // VGPR cap 128 (R4 lesson: never cap below live set)
void afm_kernel(const int*   __restrict__ sparse,   // [B,26]
                const float* __restrict__ dense,    // [B,13]
                const float* __restrict__ etab,     // [V,64]
                const float* __restrict__ ltab,     // [V]
                const float* __restrict__ wdense,   // [13]
                const float* __restrict__ bias,     // [1]
                const float* __restrict__ W1,       // [64][64] f32, d-major
                const float* __restrict__ b1,       // [64]
                const float* __restrict__ w2,       // [64]
                const float* __restrict__ proj,     // [64]
                float*       __restrict__ out,      // [B]
                int B)
{
    const int t    = threadIdx.x;
    const int wave = t >> 6;
    const int lane = t & 63;
    const int qd   = lane >> 4;     // quad 0..3
    const int ln   = lane & 15;

    __shared__ alignas(16) _Float16       w1t_s[AF][WSTRIDE];      //  9216 B (row a, col d)
    __shared__              unsigned short tab_s[NMT * 16];        //   672 B
    __shared__ alignas(16) _Float16       emb_all[WPB][NF][ESTRIDE]; // 14976 B

    // ---- block-cooperative W1 -> W1^T staging (coalesced f32 reads,
    //      one-time transposed f16 LDS writes; W1 is 16 KB, L2-hot) ----
    for (int idx = t; idx < ED * AF; idx += BLOCK) {
        int d = idx >> 6, a = idx & 63;       // W1 is [d][a]
        w1t_s[a][d] = (_Float16)W1[idx];
    }
    // ---- pair-index table: tab_s[p] = i | j<<8 ----
    for (int p = t; p < NMT * 16; p += BLOCK) {
        unsigned short v = 0;
        if (p < NP) {
            int rem = p, i = 0;
            while (rem >= NF - 1 - i) { rem -= NF - 1 - i; ++i; }
            v = (unsigned short)(i | ((i + 1 + rem) << 8));
        }
        tab_s[p] = v;
    }

    const int r = blockIdx.x * WPB + wave;   // this wave's batch row
    const bool active = (r < B);

    _Float16 (* __restrict__ emb)[ESTRIDE] = emb_all[wave];
    float lin = 0.f;
    float4 b1v4[4], w2v4[4];

    if (active) {
        // ---- stage this row's 26 embeddings into LDS as f16, b128 writes ----
        const int* __restrict__ srow = sparse + r * NF;
        for (int task = lane; task < NF * 8; task += 64) {
            int f = task >> 3, c = task & 7;                 // 8-half chunk
            const float* src = etab + (size_t)srow[f] * ED + c * 8;
            float4 v0 = *(const float4*)(src);
            float4 v1 = *(const float4*)(src + 4);
            half8 h = { (_Float16)v0.x, (_Float16)v0.y, (_Float16)v0.z, (_Float16)v0.w,
                        (_Float16)v1.x, (_Float16)v1.y, (_Float16)v1.z, (_Float16)v1.w };
            *(half8*)(&emb[f][c * 8]) = h;
        }

        // b1/w2 for af = nt*16 + qd*4 + rr  (C-row mapping) -- overlap with staging
        #pragma unroll
        for (int nt = 0; nt < 4; ++nt) {
            b1v4[nt] = *(const float4*)(b1 + nt * 16 + qd * 4);
            w2v4[nt] = *(const float4*)(w2 + nt * 16 + qd * 4);
        }

        // ---- linear part (wave-local registers) ----
        if (lane < NF) {
            lin = ltab[srow[lane]];
        } else if (lane >= 32 && lane < 32 + NDENSE) {
            int k = lane - 32;
            lin = dense[r * NDENSE + k] * wdense[k];
        }
        #pragma unroll
        for (int off = 32; off >= 1; off >>= 1) lin += __shfl_xor(lin, off, 64);
        lin += bias[0];
    }

    __syncthreads();          // w1t_s/tab_s/emb visible
    if (!active) return;      // safe: no barriers after this point

    // ---- W1^T A-operand fragments from LDS:
    //      bfr[nt][kh] = w1t[af = nt*16+ln][k = kh*32 + qd*8 + j] ----
    half8 bfr[4][2];
    #pragma unroll
    for (int nt = 0; nt < 4; ++nt)
        #pragma unroll
        for (int kh = 0; kh < 2; ++kh)
            bfr[nt][kh] = *(const half8*)(&w1t_s[nt * 16 + ln][kh * 32 + qd * 8]);

    // ---- fused main loop: logits via operand-swapped MFMA + online softmax.
    //      Lane state: m (running max), l (running denom), acc0/acc1 (f16,
    //      dims qd*8..+7 and 32+qd*8..+7) accumulating e_p * x_p[d]. ----
    float m = -INFINITY, l = 0.f;
    half8 acc0 = { (_Float16)0.f, (_Float16)0.f, (_Float16)0.f, (_Float16)0.f,
                   (_Float16)0.f, (_Float16)0.f, (_Float16)0.f, (_Float16)0.f };
    half8 acc1 = acc0;

    // depth-1 pipeline: prefetch next mt's tab + emb fragments
    unsigned pp = tab_s[ln];                     // mt=0
    int fi = pp & 0xff, fj = pp >> 8;
    half8 ei0 = *(const half8*)(&emb[fi][qd * 8]);
    half8 ei1 = *(const half8*)(&emb[fi][32 + qd * 8]);
    half8 ej0 = *(const half8*)(&emb[fj][qd * 8]);
    half8 ej1 = *(const half8*)(&emb[fj][32 + qd * 8]);

    for (int mt = 0; mt < NMT; ++mt) {
        half8 x0 = ei0 * ej0;                    // pair product, in registers
        half8 x1 = ei1 * ej1;

        if (mt + 1 < NMT) {                      // issue next tile's loads now
            unsigned np = tab_s[(mt + 1) * 16 + ln];
            int nfi = np & 0xff, nfj = np >> 8;
            ei0 = *(const half8*)(&emb[nfi][qd * 8]);
            ei1 = *(const half8*)(&emb[nfi][32 + qd * 8]);
            ej0 = *(const half8*)(&emb[nfj][qd * 8]);
            ej1 = *(const half8*)(&emb[nfj][32 + qd * 8]);
        }

        // logits: D[m=af][n=pair=ln]; C rows = qd*4+reg = af within nt*16.
        // Per-nt partial sums + 2-level tree (dep chain ~20 cyc vs 64 serial).
        float lgp[4];
        #pragma unroll
        for (int nt = 0; nt < 4; ++nt) {
            f32x4 acc = { b1v4[nt].x, b1v4[nt].y, b1v4[nt].z, b1v4[nt].w };
            acc = __builtin_amdgcn_mfma_f32_16x16x32_f16(bfr[nt][0], x0, acc, 0, 0, 0);
            acc = __builtin_amdgcn_mfma_f32_16x16x32_f16(bfr[nt][1], x1, acc, 0, 0, 0);
            float u = fmaf(fmaxf(acc[1], 0.f), w2v4[nt].y, fmaxf(acc[0], 0.f) * w2v4[nt].x);
            float v = fmaf(fmaxf(acc[3], 0.f), w2v4[nt].w, fmaxf(acc[2], 0.f) * w2v4[nt].z);
            lgp[nt] = u + v;
        }
        float lg = (lgp[0] + lgp[1]) + (lgp[2] + lgp[3]);
        // sum over the 4 qd groups -> full 64-af logit, replicated across qd
        lg += __shfl_xor(lg, 16, 64);
        lg += __shfl_xor(lg, 32, 64);

        const int p0 = mt * 16 + ln;
        if (p0 >= NP) lg = -INFINITY;            // pad pairs contribute 0

        // online-softmax update (per-lane running state)
        float mn    = fmaxf(m, lg);
        float alpha = __expf(m - mn);            // m=-inf first iter -> 0
        float e     = __expf(lg - mn);           // lg=-inf pad -> 0
        l = l * alpha + e;
        m = mn;
        _Float16 ah = (_Float16)alpha, eh = (_Float16)e;
        half8 a8 = { ah, ah, ah, ah, ah, ah, ah, ah };
        half8 e8 = { eh, eh, eh, eh, eh, eh, eh, eh };
        acc0 = acc0 * a8 + x0 * e8;              // v_pk_fma_f16
        acc1 = acc1 * a8 + x1 * e8;
    }

    // ---- merge: lanes sharing qd (ln = bits 0..3) cover all 336 pairs ----
    float mg = m;
    #pragma unroll
    for (int off = 1; off <= 8; off <<= 1) mg = fmaxf(mg, __shfl_xor(mg, off, 64));
    const float fac = __expf(m - mg);            // per-lane rescale to global max
    float lsum = l * fac;
    #pragma unroll
    for (int off = 1; off <= 8; off <<= 1) lsum += __shfl_xor(lsum, off, 64);
    // lsum now = global softmax denominator, identical across qd groups

    // proj-dot in-lane (dims qd*8..+7 and 32+qd*8..+7), scaled by fac
    float4 pa = *(const float4*)(proj + qd * 8);
    float4 pb = *(const float4*)(proj + qd * 8 + 4);
    float4 pc = *(const float4*)(proj + 32 + qd * 8);
    float4 pd = *(const float4*)(proj + 32 + qd * 8 + 4);
    float rr = (float)acc0[0] * pa.x + (float)acc0[1] * pa.y
             + (float)acc0[2] * pa.z + (float)acc0[3] * pa.w
             + (float)acc0[4] * pb.x + (float)acc0[5] * pb.y
             + (float)acc0[6] * pb.z + (float)acc0[7] * pb.w
             + (float)acc1[0] * pc.x + (float)acc1[1] * pc.y
             + (float)acc1[2] * pc.z + (float)acc1[3] * pc.w
             + (float)acc1[4] * pd.x + (float)acc1[5] * pd.y
             + (float)acc1[6] * pd.z + (float)acc1[7] * pd.w;
    rr *= fac;
    // sum over ln (pairs) and qd (dim chunks): all 6 lane bits
    #pragma unroll
    for (int off = 1; off <= 32; off <<= 1) rr += __shfl_xor(rr, off, 64);

    if (lane == 0) out[r] = lin + rr / lsum;
}

extern "C" void kernel_launch(void* const* d_in, const int* in_sizes, int n_in,
                              void* d_out, int out_size, void* d_ws, size_t ws_size,
                              hipStream_t stream) {
    const int*   sparse = (const int*)  d_in[0];
    const float* dense  = (const float*)d_in[1];
    const float* etab   = (const float*)d_in[2];
    const float* ltab   = (const float*)d_in[3];
    const float* wdense = (const float*)d_in[4];
    const float* bias   = (const float*)d_in[5];
    const float* W1     = (const float*)d_in[6];
    const float* b1     = (const float*)d_in[7];
    const float* w2     = (const float*)d_in[8];
    const float* proj   = (const float*)d_in[9];
    float* outp = (float*)d_out;

    const int B = in_sizes[0] / NF;

    afm_kernel<<<dim3((B + WPB - 1) / WPB), dim3(BLOCK), 0, stream>>>(
        sparse, dense, etab, ltab, wdense, bias, W1, b1, w2, proj, outp, B);
    (void)n_in; (void)out_size; (void)d_ws; (void)ws_size;
}